// Round 5
// baseline (2269.111 us; speedup 1.0000x reference)
//
#include <hip/hip_runtime.h>

// ---------------- problem constants ----------------
#define D_SZ 512
#define S_SZ 1024
#define H_SZ 2048
#define BS_SZ 32768
#define H_STEP 0.1f

typedef __attribute__((ext_vector_type(4))) float f32x4;
typedef __attribute__((ext_vector_type(8))) short s16x8;
typedef __attribute__((ext_vector_type(4))) unsigned short u16x4;
typedef unsigned short ushort_t;

__device__ __forceinline__ ushort_t f2b(float f) {
    unsigned u = __float_as_uint(f);
    unsigned r = (u + 0x7FFFu + ((u >> 16) & 1u)) >> 16;
    return (ushort_t)r;
}

__device__ __forceinline__ void gload_lds16(const void* g, void* l) {
    __builtin_amdgcn_global_load_lds(
        (const __attribute__((address_space(1))) unsigned int*)g,
        (__attribute__((address_space(3))) unsigned int*)l, 16, 0, 0);
}

// ---------------- prep kernels ----------------
__global__ void prep_w1(const float* __restrict__ W1,
                        ushort_t* __restrict__ W1b,
                        ushort_t* __restrict__ W1T) {
    int idx = blockIdx.x * 256 + threadIdx.x;   // over H*D = 1M
    float v = W1[idx];
    ushort_t b = f2b(v);
    int h = idx >> 9;          // / 512
    int d = idx & 511;
    W1b[idx] = b;
    W1T[(size_t)d * H_SZ + h] = b;
}

__global__ void prep_mass(const float* __restrict__ logm,
                          float* __restrict__ inv_mass,
                          float* __restrict__ mass) {
    int s = blockIdx.x * 256 + threadIdx.x;
    if (s < S_SZ) {
        float lm = logm[s];
        mass[s] = expf(lm);
        inv_mass[s] = expf(-lm);
    }
}

// ---------------- embedding + p0 ----------------
__global__ void embed_kernel(const float* __restrict__ table,
                             const int* __restrict__ ids,
                             const float* __restrict__ mass,
                             float* __restrict__ q,
                             float* __restrict__ p,
                             ushort_t* __restrict__ qb) {
    int i = blockIdx.x;          // row index in [0, BS)
    int t = threadIdx.x;
    int s = i & (S_SZ - 1);
    int id = ids[i];
    int idp = (s == 0) ? id : ids[i - 1];   // s==0: prev = self -> vel 0
    float mk = (id != 0) ? 1.f : 0.f;
    float ms = mass[s];
    int d0 = t * 4;

    f32x4 cur = {0.f, 0.f, 0.f, 0.f};
    f32x4 prv = {0.f, 0.f, 0.f, 0.f};
    if (id != 0)  cur = *(const f32x4*)(table + (size_t)id  * D_SZ + d0);
    if (idp != 0) prv = *(const f32x4*)(table + (size_t)idp * D_SZ + d0);

    size_t off = (size_t)i * D_SZ + d0;
    *(f32x4*)(q + off) = cur;
    u16x4 cb;
    cb[0] = f2b(cur[0]); cb[1] = f2b(cur[1]); cb[2] = f2b(cur[2]); cb[3] = f2b(cur[3]);
    *(u16x4*)(qb + off) = cb;

    f32x4 pv;
    pv[0] = ms * (cur[0] - prv[0]) * mk;
    pv[1] = ms * (cur[1] - prv[1]) * mk;
    pv[2] = ms * (cur[2] - prv[2]) * mk;
    pv[3] = ms * (cur[3] - prv[3]) * mk;
    *(f32x4*)(p + off) = pv;
}

// =====================================================================
// force1, persistent-lite: grid 256, block owns 128 i-rows, loops 8
// h-segments of 256 as one flat 128-tile pipeline (BK=32, 3 bufs, 2-deep,
// vmcnt(3)). Per segment: C[h=256][i=128] -> U[i,h] = sech2(C+b1)*w2.
// 8 waves (4h x 2i), per-wave 64x64, acc[4][4].
// =====================================================================
__global__ __launch_bounds__(512, 2) void gemm_f1(
        const ushort_t* __restrict__ W1b,   // [2048, 512]
        const ushort_t* __restrict__ qb,    // [BS, 512]
        const float* __restrict__ b1,
        const float* __restrict__ W2,
        ushort_t* __restrict__ U) {
    __shared__ __align__(16) ushort_t lA[3][256 * 32];   // 48 KB
    __shared__ __align__(16) ushort_t lB[3][128 * 32];   // 24 KB

    const int tid = threadIdx.x;
    const int lane = tid & 63, wid = tid >> 6;
    const int wm = wid >> 1, wn = wid & 1;     // 4 x 2 wave grid (h x i)
    const int lr = lane & 15, lk = lane >> 4;

    const long b0 = (long)blockIdx.x * 128;

    // staging: A = 1024 chunks (2/thread, rows r0 and r0+128), B = 512 (1/thread)
    const int r0  = tid >> 2;                 // 0..127
    const int kc  = tid & 3;
    const int kcs = kc ^ ((r0 >> 1) & 3);     // same for r0+128
    const ushort_t* gA = W1b + (long)r0 * D_SZ + kcs * 8;
    const ushort_t* gB = qb + (b0 + r0) * (long)D_SZ + kcs * 8;
    const int ldA1 = tid * 8, ldA2 = (tid + 512) * 8, ldB = tid * 8;

    // tt = hb*16 + kt over 128 flat tiles
#define STAGE(tt) { int _b = (tt) % 3; int _hb = (tt) >> 4; int _kt = (tt) & 15; \
    gload_lds16(gA + (long)_hb * (256 * D_SZ) + _kt * 32,              &lA[_b][ldA1]); \
    gload_lds16(gA + (long)_hb * (256 * D_SZ) + 128 * D_SZ + _kt * 32, &lA[_b][ldA2]); \
    gload_lds16(gB + _kt * 32,                                         &lB[_b][ldB]); }

    f32x4 acc[4][4];
    #pragma unroll
    for (int m = 0; m < 4; ++m)
        #pragma unroll
        for (int n = 0; n < 4; ++n)
            acc[m][n] = (f32x4){0.f, 0.f, 0.f, 0.f};

    const int lks8 = (lk ^ ((lr >> 1) & 3)) * 8;
    const int roA = (wm * 64 + lr) * 32 + lks8;   // + m*512
    const int roB = (wn * 64 + lr) * 32 + lks8;   // + n*512

    STAGE(0);
    STAGE(1);

    for (int tt = 0; tt < 128; ++tt) {
        const int buf = tt % 3;
        const ushort_t* bA = &lA[buf][0];
        const ushort_t* bB = &lB[buf][0];
        if (tt < 127) asm volatile("s_waitcnt vmcnt(3)" ::: "memory");
        else          asm volatile("s_waitcnt vmcnt(0)" ::: "memory");
        __builtin_amdgcn_s_barrier();
        asm volatile("" ::: "memory");

        s16x8 av[4], bv[4];
        #pragma unroll
        for (int m = 0; m < 4; ++m) av[m] = *(const s16x8*)&bA[roA + m * 512];
        #pragma unroll
        for (int n = 0; n < 4; ++n) bv[n] = *(const s16x8*)&bB[roB + n * 512];
        __builtin_amdgcn_s_setprio(1);
        #pragma unroll
        for (int m = 0; m < 4; ++m)
            #pragma unroll
            for (int n = 0; n < 4; ++n)
                acc[m][n] = __builtin_amdgcn_mfma_f32_16x16x32_bf16(av[m], bv[n], acc[m][n], 0, 0, 0);
        __builtin_amdgcn_s_setprio(0);
        __builtin_amdgcn_s_barrier();
        asm volatile("" ::: "memory");

        if ((tt & 15) == 15) {
            // segment epilogue: write U for h-block hb, reset acc
            int hb = tt >> 4;
            #pragma unroll
            for (int m = 0; m < 4; ++m) {
                long h0 = hb * 256 + wm * 64 + m * 16 + lk * 4;
                f32x4 b1v = *(const f32x4*)(b1 + h0);
                f32x4 w2v = *(const f32x4*)(W2 + h0);
                #pragma unroll
                for (int n = 0; n < 4; ++n) {
                    long i = b0 + wn * 64 + n * 16 + lr;
                    u16x4 ub;
                    #pragma unroll
                    for (int j = 0; j < 4; ++j) {
                        float uu = acc[m][n][j] + b1v[j];
                        float e = __expf(-2.0f * fabsf(uu));
                        float rc = 1.0f / (1.0f + e);
                        ub[j] = f2b(4.0f * e * rc * rc * w2v[j]);
                    }
                    *(u16x4*)(U + i * H_SZ + h0) = ub;
                    acc[m][n] = (f32x4){0.f, 0.f, 0.f, 0.f};
                }
            }
        }
        if (tt + 2 < 128) STAGE(tt + 2);
    }
#undef STAGE
}

// =====================================================================
// force2: grid 256, block owns 128 i-rows x ALL 512 d. A = full W1T
// (L2-shared by every block), B = U i-tile. K=2048, BK=32, 3 bufs,
// 2-deep, vmcnt(5). 8 waves (4d x 2i), per-wave 128x64, acc[8][4].
// Epilogue: p -= coef*mask*G ; q += 0.1*p/m*mask ; qb = bf16(q).
// =====================================================================
__global__ __launch_bounds__(512, 2) void gemm_f2(
        const ushort_t* __restrict__ W1T,   // [512, 2048]
        const ushort_t* __restrict__ U,     // [BS, 2048]
        const int* __restrict__ ids,
        const float* __restrict__ inv_mass,
        float* __restrict__ q,
        float* __restrict__ p,
        ushort_t* __restrict__ qb,
        float coef, int do_q) {
    __shared__ __align__(16) ushort_t lA[3][512 * 32];   // 96 KB
    __shared__ __align__(16) ushort_t lB[3][128 * 32];   // 24 KB

    const int tid = threadIdx.x;
    const int lane = tid & 63, wid = tid >> 6;
    const int wm = wid >> 1, wn = wid & 1;     // 4 x 2 wave grid (d x i)
    const int lr = lane & 15, lk = lane >> 4;

    const long b0 = (long)blockIdx.x * 128;

    // staging: A = 4096 chunks (4/thread, rows r0+128k), B = 512 (1/thread)
    const int r0  = tid >> 2;                 // 0..127
    const int kc  = tid & 3;
    const int kcs = kc ^ ((r0 >> 1) & 3);     // same for r0+128k
    const ushort_t* gA = W1T + (long)r0 * H_SZ + kcs * 8;
    const ushort_t* gB = U + (b0 + r0) * (long)H_SZ + kcs * 8;

#define STAGE(t) { int _b = (t) % 3;                                     \
    gload_lds16(gA + (t) * 32,                  &lA[_b][tid * 8]);        \
    gload_lds16(gA + 128 * H_SZ + (t) * 32,     &lA[_b][(tid + 512) * 8]);\
    gload_lds16(gA + 256 * H_SZ + (t) * 32,     &lA[_b][(tid + 1024) * 8]);\
    gload_lds16(gA + 384 * H_SZ + (t) * 32,     &lA[_b][(tid + 1536) * 8]);\
    gload_lds16(gB + (t) * 32,                  &lB[_b][tid * 8]); }

    f32x4 acc[8][4];
    #pragma unroll
    for (int m = 0; m < 8; ++m)
        #pragma unroll
        for (int n = 0; n < 4; ++n)
            acc[m][n] = (f32x4){0.f, 0.f, 0.f, 0.f};

    const int lks8 = (lk ^ ((lr >> 1) & 3)) * 8;
    const int roA = (wm * 128 + lr) * 32 + lks8;  // + m*512 (m=0..7)
    const int roB = (wn * 64 + lr) * 32 + lks8;   // + n*512

    STAGE(0);
    STAGE(1);

    const int NT = H_SZ / 32;   // 64
    for (int t = 0; t < NT; ++t) {
        const int buf = t % 3;
        const ushort_t* bA = &lA[buf][0];
        const ushort_t* bB = &lB[buf][0];
        if (t < NT - 1) asm volatile("s_waitcnt vmcnt(5)" ::: "memory");
        else            asm volatile("s_waitcnt vmcnt(0)" ::: "memory");
        __builtin_amdgcn_s_barrier();
        asm volatile("" ::: "memory");

        s16x8 bv[4];
        #pragma unroll
        for (int n = 0; n < 4; ++n) bv[n] = *(const s16x8*)&bB[roB + n * 512];
        #pragma unroll
        for (int mh = 0; mh < 2; ++mh) {
            s16x8 av[4];
            #pragma unroll
            for (int m = 0; m < 4; ++m) av[m] = *(const s16x8*)&bA[roA + (mh * 4 + m) * 512];
            __builtin_amdgcn_s_setprio(1);
            #pragma unroll
            for (int m = 0; m < 4; ++m)
                #pragma unroll
                for (int n = 0; n < 4; ++n)
                    acc[mh * 4 + m][n] = __builtin_amdgcn_mfma_f32_16x16x32_bf16(av[m], bv[n], acc[mh * 4 + m][n], 0, 0, 0);
            __builtin_amdgcn_s_setprio(0);
        }
        __builtin_amdgcn_s_barrier();
        asm volatile("" ::: "memory");
        if (t + 2 < NT) STAGE(t + 2);
    }
#undef STAGE

    // epilogue: per i row this wave owns, full 128-d slice (wm) is contiguous
    #pragma unroll
    for (int n = 0; n < 4; ++n) {
        long i = b0 + wn * 64 + n * 16 + lr;
        int id = ids[i];
        float cm = (id != 0) ? coef : 0.f;
        float hm = (id != 0) ? H_STEP : 0.f;
        float im = inv_mass[(int)(i & (S_SZ - 1))];
        #pragma unroll
        for (int m = 0; m < 8; ++m) {
            long d0 = wm * 128 + m * 16 + lk * 4;
            size_t off = (size_t)i * D_SZ + d0;
            f32x4 pv = *(const f32x4*)(p + off);
            #pragma unroll
            for (int j = 0; j < 4; ++j)
                pv[j] -= cm * acc[m][n][j];
            *(f32x4*)(p + off) = pv;
            if (do_q) {
                f32x4 qv = *(const f32x4*)(q + off);
                u16x4 qbv;
                #pragma unroll
                for (int j = 0; j < 4; ++j) {
                    qv[j] += hm * pv[j] * im;
                    qbv[j] = f2b(qv[j]);
                }
                *(f32x4*)(q + off) = qv;
                *(u16x4*)(qb + off) = qbv;
            }
        }
    }
}

// ---------------- host launch ----------------
extern "C" void kernel_launch(void* const* d_in, const int* in_sizes, int n_in,
                              void* d_out, int out_size, void* d_ws, size_t ws_size,
                              hipStream_t stream) {
    const float* table = (const float*)d_in[0];
    const float* logm  = (const float*)d_in[1];
    const float* W1    = (const float*)d_in[2];
    const float* b1    = (const float*)d_in[3];
    const float* W2    = (const float*)d_in[4];
    // d_in[5] = b2, unused by the force (only shifts the potential value)
    const int*   ids   = (const int*)d_in[6];

    float* q = (float*)d_out;                       // [BS, D]
    float* p = q + (size_t)BS_SZ * D_SZ;            // [BS, D]

    char* ws = (char*)d_ws;
    size_t o = 0;
    ushort_t* qb  = (ushort_t*)(ws + o); o += (size_t)BS_SZ * D_SZ * 2;   // 32 MB
    ushort_t* U   = (ushort_t*)(ws + o); o += (size_t)BS_SZ * H_SZ * 2;   // 128 MB
    ushort_t* W1b = (ushort_t*)(ws + o); o += (size_t)H_SZ * D_SZ * 2;    // 2 MB
    ushort_t* W1T = (ushort_t*)(ws + o); o += (size_t)D_SZ * H_SZ * 2;    // 2 MB
    float* inv_mass = (float*)(ws + o);  o += S_SZ * 4;
    float* mass     = (float*)(ws + o);  o += S_SZ * 4;

    prep_w1<<<(H_SZ * D_SZ) / 256, 256, 0, stream>>>(W1, W1b, W1T);
    prep_mass<<<(S_SZ + 255) / 256, 256, 0, stream>>>(logm, inv_mass, mass);
    embed_kernel<<<BS_SZ, 128, 0, stream>>>(table, ids, mass, q, p, qb);

    // 6 distinct force evals: j=0 -> +0.05*f(q0); j=1..4 -> +0.1*f(qj); j=5 -> +0.05*f(q5)
    for (int j = 0; j < 6; ++j) {
        gemm_f1<<<256, 512, 0, stream>>>(W1b, qb, b1, W2, U);
        float coef = (j == 0 || j == 5) ? 0.05f : 0.1f;
        gemm_f2<<<256, 512, 0, stream>>>(
            W1T, U, ids, inv_mass, q, p, qb, coef, (j < 5) ? 1 : 0);
    }
}

// Round 6
// 1564.193 us; speedup vs baseline: 1.4507x; 1.4507x over previous
//
#include <hip/hip_runtime.h>

// ---------------- problem constants ----------------
#define D_SZ 512
#define S_SZ 1024
#define H_SZ 2048
#define BS_SZ 32768
#define H_STEP 0.1f

typedef __attribute__((ext_vector_type(4))) float f32x4;
typedef __attribute__((ext_vector_type(8))) short s16x8;
typedef __attribute__((ext_vector_type(4))) unsigned short u16x4;
typedef unsigned short ushort_t;

__device__ __forceinline__ ushort_t f2b(float f) {
    unsigned u = __float_as_uint(f);
    unsigned r = (u + 0x7FFFu + ((u >> 16) & 1u)) >> 16;
    return (ushort_t)r;
}

__device__ __forceinline__ void gload_lds16(const void* g, void* l) {
    __builtin_amdgcn_global_load_lds(
        (const __attribute__((address_space(1))) unsigned int*)g,
        (__attribute__((address_space(3))) unsigned int*)l, 16, 0, 0);
}

// ---------------- prep kernels ----------------
__global__ void prep_w1(const float* __restrict__ W1,
                        ushort_t* __restrict__ W1b,
                        ushort_t* __restrict__ W1T) {
    int idx = blockIdx.x * 256 + threadIdx.x;   // over H*D = 1M
    float v = W1[idx];
    ushort_t b = f2b(v);
    int h = idx >> 9;          // / 512
    int d = idx & 511;
    W1b[idx] = b;
    W1T[(size_t)d * H_SZ + h] = b;
}

__global__ void prep_mass(const float* __restrict__ logm,
                          float* __restrict__ inv_mass,
                          float* __restrict__ mass) {
    int s = blockIdx.x * 256 + threadIdx.x;
    if (s < S_SZ) {
        float lm = logm[s];
        mass[s] = expf(lm);
        inv_mass[s] = expf(-lm);
    }
}

// ---------------- embedding + p0 ----------------
__global__ void embed_kernel(const float* __restrict__ table,
                             const int* __restrict__ ids,
                             const float* __restrict__ mass,
                             float* __restrict__ q,
                             float* __restrict__ p,
                             ushort_t* __restrict__ qb) {
    int i = blockIdx.x;          // row index in [0, BS)
    int t = threadIdx.x;
    int s = i & (S_SZ - 1);
    int id = ids[i];
    int idp = (s == 0) ? id : ids[i - 1];   // s==0: prev = self -> vel 0
    float mk = (id != 0) ? 1.f : 0.f;
    float ms = mass[s];
    int d0 = t * 4;

    f32x4 cur = {0.f, 0.f, 0.f, 0.f};
    f32x4 prv = {0.f, 0.f, 0.f, 0.f};
    if (id != 0)  cur = *(const f32x4*)(table + (size_t)id  * D_SZ + d0);
    if (idp != 0) prv = *(const f32x4*)(table + (size_t)idp * D_SZ + d0);

    size_t off = (size_t)i * D_SZ + d0;
    *(f32x4*)(q + off) = cur;
    u16x4 cb;
    cb[0] = f2b(cur[0]); cb[1] = f2b(cur[1]); cb[2] = f2b(cur[2]); cb[3] = f2b(cur[3]);
    *(u16x4*)(qb + off) = cb;

    f32x4 pv;
    pv[0] = ms * (cur[0] - prv[0]) * mk;
    pv[1] = ms * (cur[1] - prv[1]) * mk;
    pv[2] = ms * (cur[2] - prv[2]) * mk;
    pv[3] = ms * (cur[3] - prv[3]) * mk;
    *(f32x4*)(p + off) = pv;
}

// =====================================================================
// force1, persistent: grid 256; block owns i-tile 256 (by) and 4 h-tiles
// of 256 (apair*1024 + ot*256). 256x256 tiles, BK=32, 4 LDS bufs,
// depth-3 prefetch, ONE barrier/tile, vmcnt(8) steady. T2 swizzle.
// Boundary order: U-stores THEN next-tile stages (stores drain under
// the first vmcnt(8), stages stay in flight).
// =====================================================================
__global__ __launch_bounds__(512, 2) void gemm_f1(
        const ushort_t* __restrict__ W1b,   // [2048, 512]
        const ushort_t* __restrict__ qb,    // [BS, 512]
        const float* __restrict__ b1,
        const float* __restrict__ W2,
        ushort_t* __restrict__ U) {
    __shared__ __align__(16) ushort_t lA[4][256 * 32];   // 64 KB
    __shared__ __align__(16) ushort_t lB[4][256 * 32];   // 64 KB

    const int tid = threadIdx.x;
    const int lane = tid & 63, wid = tid >> 6;
    const int wm = wid >> 2, wn = wid & 3;     // 2 (h) x 4 (i)
    const int lr = lane & 15, lk = lane >> 4;

    int wgid = ((int)blockIdx.x & 7) * 32 + ((int)blockIdx.x >> 3);
    const int apair = wgid & 1;                // 0/1 -> h 0..1023 / 1024..2047
    const long b0 = (long)(wgid >> 1) * 256;   // i base

    const int r0  = tid >> 2;
    const int kc  = tid & 3;
    const int kcs = kc ^ ((r0 >> 1) & 3);
    const ushort_t* gB1 = qb + (b0 + r0) * (long)D_SZ + kcs * 8;
    const ushort_t* gB2 = gB1 + (long)128 * D_SZ;
    const ushort_t* gA1;                       // set per output tile

#define STAGE1(k) { int _b = (k) & 3;                                    \
    gload_lds16(gA1 + (k) * 32,                 &lA[_b][tid * 8]);        \
    gload_lds16(gA1 + 128 * D_SZ + (k) * 32,    &lA[_b][(tid + 512) * 8]);\
    gload_lds16(gB1 + (k) * 32,                 &lB[_b][tid * 8]);        \
    gload_lds16(gB2 + (k) * 32,                 &lB[_b][(tid + 512) * 8]); }

    f32x4 acc[8][4];
    #pragma unroll
    for (int m = 0; m < 8; ++m)
        #pragma unroll
        for (int n = 0; n < 4; ++n)
            acc[m][n] = (f32x4){0.f, 0.f, 0.f, 0.f};

    const int lks8 = (lk ^ ((lr >> 1) & 3)) * 8;
    const int roA = (wm * 128 + lr) * 32 + lks8;   // + m*512
    const int roB = (wn * 64 + lr) * 32 + lks8;    // + n*512

    for (int ot = 0; ot < 4; ++ot) {
        const int a0 = (apair * 4 + ot) * 256;     // h base
        if (ot == 0) {
            gA1 = W1b + (long)(a0 + r0) * D_SZ + kcs * 8;
            STAGE1(0); STAGE1(1); STAGE1(2);
        }
        for (int k = 0; k < 16; ++k) {
            const ushort_t* bA = &lA[k & 3][0];
            const ushort_t* bB = &lB[k & 3][0];
            if (k < 14)      asm volatile("s_waitcnt vmcnt(8)" ::: "memory");
            else if (k == 14) asm volatile("s_waitcnt vmcnt(4)" ::: "memory");
            else             asm volatile("s_waitcnt vmcnt(0)" ::: "memory");
            __builtin_amdgcn_s_barrier();
            asm volatile("" ::: "memory");

            s16x8 av[8], bv[4];
            #pragma unroll
            for (int m = 0; m < 8; ++m) av[m] = *(const s16x8*)&bA[roA + m * 512];
            #pragma unroll
            for (int n = 0; n < 4; ++n) bv[n] = *(const s16x8*)&bB[roB + n * 512];
            if (k < 13) STAGE1(k + 3);
            __builtin_amdgcn_s_setprio(1);
            #pragma unroll
            for (int m = 0; m < 8; ++m)
                #pragma unroll
                for (int n = 0; n < 4; ++n)
                    acc[m][n] = __builtin_amdgcn_mfma_f32_16x16x32_bf16(av[m], bv[n], acc[m][n], 0, 0, 0);
            __builtin_amdgcn_s_setprio(0);
        }

        // ---- epilogue: U[i,h] = bf16(sech2(C+b1)*w2), then reset acc
        #pragma unroll
        for (int m = 0; m < 8; ++m) {
            long h0 = a0 + wm * 128 + m * 16 + lk * 4;
            f32x4 b1v = *(const f32x4*)(b1 + h0);
            f32x4 w2v = *(const f32x4*)(W2 + h0);
            #pragma unroll
            for (int n = 0; n < 4; ++n) {
                long i = b0 + wn * 64 + n * 16 + lr;
                u16x4 ub;
                #pragma unroll
                for (int j = 0; j < 4; ++j) {
                    float uu = acc[m][n][j] + b1v[j];
                    float e = __expf(-2.0f * fabsf(uu));
                    float rc = 1.0f / (1.0f + e);
                    ub[j] = f2b(4.0f * e * rc * rc * w2v[j]);
                }
                *(u16x4*)(U + i * H_SZ + h0) = ub;
                acc[m][n] = (f32x4){0.f, 0.f, 0.f, 0.f};
            }
        }
        // ---- stage next tile AFTER stores (stores drain first in FIFO)
        if (ot < 3) {
            gA1 = W1b + (long)((apair * 4 + ot + 1) * 256 + r0) * D_SZ + kcs * 8;
            STAGE1(0); STAGE1(1); STAGE1(2);
        }
    }
#undef STAGE1
}

// =====================================================================
// force2: grid 256 = 2 d-blocks x 128 i-blocks, 256x256 tile, K=2048,
// BK=32, 4 LDS bufs, depth-3, ONE barrier/tile, vmcnt(8) steady.
// A = W1T (L2-resident), B = U stream. Epilogue: leapfrog p/q update.
// =====================================================================
__global__ __launch_bounds__(512, 2) void gemm_f2(
        const ushort_t* __restrict__ W1T,   // [512, 2048]
        const ushort_t* __restrict__ U,     // [BS, 2048]
        const int* __restrict__ ids,
        const float* __restrict__ inv_mass,
        float* __restrict__ q,
        float* __restrict__ p,
        ushort_t* __restrict__ qb,
        float coef, int do_q) {
    __shared__ __align__(16) ushort_t lA[4][256 * 32];   // 64 KB
    __shared__ __align__(16) ushort_t lB[4][256 * 32];   // 64 KB

    const int tid = threadIdx.x;
    const int lane = tid & 63, wid = tid >> 6;
    const int wm = wid >> 2, wn = wid & 3;     // 2 (d) x 4 (i)
    const int lr = lane & 15, lk = lane >> 4;

    int wgid = ((int)blockIdx.x & 7) * 32 + ((int)blockIdx.x >> 3);
    const int a0 = (wgid & 1) * 256;           // d base
    const long b0 = (long)(wgid >> 1) * 256;   // i base

    const int r0  = tid >> 2;
    const int kc  = tid & 3;
    const int kcs = kc ^ ((r0 >> 1) & 3);
    const ushort_t* gA1 = W1T + (long)(a0 + r0) * H_SZ + kcs * 8;
    const ushort_t* gB1 = U + (b0 + r0) * (long)H_SZ + kcs * 8;
    const ushort_t* gB2 = gB1 + (long)128 * H_SZ;

#define STAGE2(k) { int _b = (k) & 3;                                    \
    gload_lds16(gA1 + (k) * 32,                 &lA[_b][tid * 8]);        \
    gload_lds16(gA1 + 128 * H_SZ + (k) * 32,    &lA[_b][(tid + 512) * 8]);\
    gload_lds16(gB1 + (k) * 32,                 &lB[_b][tid * 8]);        \
    gload_lds16(gB2 + (k) * 32,                 &lB[_b][(tid + 512) * 8]); }

    f32x4 acc[8][4];
    #pragma unroll
    for (int m = 0; m < 8; ++m)
        #pragma unroll
        for (int n = 0; n < 4; ++n)
            acc[m][n] = (f32x4){0.f, 0.f, 0.f, 0.f};

    const int lks8 = (lk ^ ((lr >> 1) & 3)) * 8;
    const int roA = (wm * 128 + lr) * 32 + lks8;   // + m*512
    const int roB = (wn * 64 + lr) * 32 + lks8;    // + n*512

    STAGE2(0); STAGE2(1); STAGE2(2);

    const int NT = H_SZ / 32;   // 64
    for (int t = 0; t < NT; ++t) {
        const ushort_t* bA = &lA[t & 3][0];
        const ushort_t* bB = &lB[t & 3][0];
        if (t < NT - 2)      asm volatile("s_waitcnt vmcnt(8)" ::: "memory");
        else if (t == NT - 2) asm volatile("s_waitcnt vmcnt(4)" ::: "memory");
        else                 asm volatile("s_waitcnt vmcnt(0)" ::: "memory");
        __builtin_amdgcn_s_barrier();
        asm volatile("" ::: "memory");

        s16x8 av[8], bv[4];
        #pragma unroll
        for (int m = 0; m < 8; ++m) av[m] = *(const s16x8*)&bA[roA + m * 512];
        #pragma unroll
        for (int n = 0; n < 4; ++n) bv[n] = *(const s16x8*)&bB[roB + n * 512];
        if (t + 3 < NT) STAGE2(t + 3);
        __builtin_amdgcn_s_setprio(1);
        #pragma unroll
        for (int m = 0; m < 8; ++m)
            #pragma unroll
            for (int n = 0; n < 4; ++n)
                acc[m][n] = __builtin_amdgcn_mfma_f32_16x16x32_bf16(av[m], bv[n], acc[m][n], 0, 0, 0);
        __builtin_amdgcn_s_setprio(0);
    }
#undef STAGE2

    // epilogue: p -= coef*mask*G ; q += 0.1*p/m*mask ; qb = bf16(q)
    #pragma unroll
    for (int n = 0; n < 4; ++n) {
        long i = b0 + wn * 64 + n * 16 + lr;
        int id = ids[i];
        float cm = (id != 0) ? coef : 0.f;
        float hm = (id != 0) ? H_STEP : 0.f;
        float im = inv_mass[(int)(i & (S_SZ - 1))];
        #pragma unroll
        for (int m = 0; m < 8; ++m) {
            long d0 = a0 + wm * 128 + m * 16 + lk * 4;
            size_t off = (size_t)i * D_SZ + d0;
            f32x4 pv = *(const f32x4*)(p + off);
            #pragma unroll
            for (int j = 0; j < 4; ++j)
                pv[j] -= cm * acc[m][n][j];
            *(f32x4*)(p + off) = pv;
            if (do_q) {
                f32x4 qv = *(const f32x4*)(q + off);
                u16x4 qbv;
                #pragma unroll
                for (int j = 0; j < 4; ++j) {
                    qv[j] += hm * pv[j] * im;
                    qbv[j] = f2b(qv[j]);
                }
                *(f32x4*)(q + off) = qv;
                *(u16x4*)(qb + off) = qbv;
            }
        }
    }
}

// ---------------- host launch ----------------
extern "C" void kernel_launch(void* const* d_in, const int* in_sizes, int n_in,
                              void* d_out, int out_size, void* d_ws, size_t ws_size,
                              hipStream_t stream) {
    const float* table = (const float*)d_in[0];
    const float* logm  = (const float*)d_in[1];
    const float* W1    = (const float*)d_in[2];
    const float* b1    = (const float*)d_in[3];
    const float* W2    = (const float*)d_in[4];
    // d_in[5] = b2, unused by the force (only shifts the potential value)
    const int*   ids   = (const int*)d_in[6];

    float* q = (float*)d_out;                       // [BS, D]
    float* p = q + (size_t)BS_SZ * D_SZ;            // [BS, D]

    char* ws = (char*)d_ws;
    size_t o = 0;
    ushort_t* qb  = (ushort_t*)(ws + o); o += (size_t)BS_SZ * D_SZ * 2;   // 32 MB
    ushort_t* U   = (ushort_t*)(ws + o); o += (size_t)BS_SZ * H_SZ * 2;   // 128 MB
    ushort_t* W1b = (ushort_t*)(ws + o); o += (size_t)H_SZ * D_SZ * 2;    // 2 MB
    ushort_t* W1T = (ushort_t*)(ws + o); o += (size_t)D_SZ * H_SZ * 2;    // 2 MB
    float* inv_mass = (float*)(ws + o);  o += S_SZ * 4;
    float* mass     = (float*)(ws + o);  o += S_SZ * 4;

    prep_w1<<<(H_SZ * D_SZ) / 256, 256, 0, stream>>>(W1, W1b, W1T);
    prep_mass<<<(S_SZ + 255) / 256, 256, 0, stream>>>(logm, inv_mass, mass);
    embed_kernel<<<BS_SZ, 128, 0, stream>>>(table, ids, mass, q, p, qb);

    // 6 distinct force evals: j=0 -> +0.05*f(q0); j=1..4 -> +0.1*f(qj); j=5 -> +0.05*f(q5)
    for (int j = 0; j < 6; ++j) {
        gemm_f1<<<256, 512, 0, stream>>>(W1b, qb, b1, W2, U);
        float coef = (j == 0 || j == 5) ? 0.05f : 0.1f;
        gemm_f2<<<256, 512, 0, stream>>>(
            W1T, U, ids, inv_mass, q, p, qb, coef, (j < 5) ? 1 : 0);
    }
}

// Round 7
// 1432.508 us; speedup vs baseline: 1.5840x; 1.0919x over previous
//
#include <hip/hip_runtime.h>

// ---------------- problem constants ----------------
#define D_SZ 512
#define S_SZ 1024
#define H_SZ 2048
#define BS_SZ 32768
#define H_STEP 0.1f

typedef __attribute__((ext_vector_type(4))) float f32x4;
typedef __attribute__((ext_vector_type(8))) short s16x8;
typedef __attribute__((ext_vector_type(4))) unsigned short u16x4;
typedef unsigned short ushort_t;

__device__ __forceinline__ ushort_t f2b(float f) {
    unsigned u = __float_as_uint(f);
    unsigned r = (u + 0x7FFFu + ((u >> 16) & 1u)) >> 16;
    return (ushort_t)r;
}

__device__ __forceinline__ void gload_lds16(const void* g, void* l) {
    __builtin_amdgcn_global_load_lds(
        (const __attribute__((address_space(1))) unsigned int*)g,
        (__attribute__((address_space(3))) unsigned int*)l, 16, 0, 0);
}

// ---------------- prep kernels ----------------
__global__ void prep_w1(const float* __restrict__ W1,
                        ushort_t* __restrict__ W1b,
                        ushort_t* __restrict__ W1T) {
    int idx = blockIdx.x * 256 + threadIdx.x;   // over H*D = 1M
    float v = W1[idx];
    ushort_t b = f2b(v);
    int h = idx >> 9;          // / 512
    int d = idx & 511;
    W1b[idx] = b;
    W1T[(size_t)d * H_SZ + h] = b;
}

__global__ void prep_mass(const float* __restrict__ logm,
                          float* __restrict__ inv_mass,
                          float* __restrict__ mass) {
    int s = blockIdx.x * 256 + threadIdx.x;
    if (s < S_SZ) {
        float lm = logm[s];
        mass[s] = expf(lm);
        inv_mass[s] = expf(-lm);
    }
}

// ---------------- embedding + p0 ----------------
__global__ void embed_kernel(const float* __restrict__ table,
                             const int* __restrict__ ids,
                             const float* __restrict__ mass,
                             float* __restrict__ q,
                             float* __restrict__ p,
                             ushort_t* __restrict__ qb) {
    int i = blockIdx.x;          // row index in [0, BS)
    int t = threadIdx.x;
    int s = i & (S_SZ - 1);
    int id = ids[i];
    int idp = (s == 0) ? id : ids[i - 1];   // s==0: prev = self -> vel 0
    float mk = (id != 0) ? 1.f : 0.f;
    float ms = mass[s];
    int d0 = t * 4;

    f32x4 cur = {0.f, 0.f, 0.f, 0.f};
    f32x4 prv = {0.f, 0.f, 0.f, 0.f};
    if (id != 0)  cur = *(const f32x4*)(table + (size_t)id  * D_SZ + d0);
    if (idp != 0) prv = *(const f32x4*)(table + (size_t)idp * D_SZ + d0);

    size_t off = (size_t)i * D_SZ + d0;
    *(f32x4*)(q + off) = cur;
    u16x4 cb;
    cb[0] = f2b(cur[0]); cb[1] = f2b(cur[1]); cb[2] = f2b(cur[2]); cb[3] = f2b(cur[3]);
    *(u16x4*)(qb + off) = cb;

    f32x4 pv;
    pv[0] = ms * (cur[0] - prv[0]) * mk;
    pv[1] = ms * (cur[1] - prv[1]) * mk;
    pv[2] = ms * (cur[2] - prv[2]) * mk;
    pv[3] = ms * (cur[3] - prv[3]) * mk;
    *(f32x4*)(p + off) = pv;
}

// =====================================================================
// m201-style fine-phase 256x256 GEMM core.
// BK=32, 4 K-tile LDS buffers (128 KB), 2 phases/tile:
//   ph_a: ds_read av[0..3]+bv[0..3] | stage A0,B0(t+3) | bar | lgkm0 | 16 MFMA | bar
//   ph_b: ds_read av[4..7] (bv held) | stage A1,B1(t+3) | vmcnt(8) | bar | lgkm0 | 16 MFMA | bar
// Prefetch distance 3 tiles (~6 phases); vmcnt(8) = iters t-1,t outstanding,
// guarantees tile t+1 staged. Stage into buf[(t+3)&3] = buf[t&3] is licensed
// by ph_b(t)'s trailing barrier (all waves done reading buf t).
// T2 swizzle identical to R3 (measured 0 conflicts). T5 setprio.
// C[r][c] = sum_k A[r,k]*B[c,k]; A rows = MAB*256, B rows = 32768.
// EPI 0: force1 (U store); EPI 1: force2 (p/q leapfrog update).
// =====================================================================
template<int KLEN, int MAB, int EPI>
__global__ __launch_bounds__(512, 2) void gemmT(
        const ushort_t* __restrict__ A,
        const ushort_t* __restrict__ B,
        const float* __restrict__ b1,
        const float* __restrict__ W2,
        ushort_t* __restrict__ U,
        const int* __restrict__ ids,
        const float* __restrict__ inv_mass,
        float* __restrict__ q,
        float* __restrict__ p,
        ushort_t* __restrict__ qb,
        float coef, int do_q) {
    constexpr int NT = KLEN / 32;
    __shared__ __align__(16) ushort_t L[4][2][256 * 32];   // [buf][A|B] 128 KB

    const int tid = threadIdx.x;
    const int lane = tid & 63, wid = tid >> 6;
    const int wm = wid >> 2, wn = wid & 3;           // 2 x 4 wave grid
    const int lr = lane & 15, lk = lane >> 4;

    // bijective XCD swizzle (nwg % 8 == 0); A-blocks fastest (share B i-tile)
    const int nwg = MAB * 128;
    int wgid = ((int)blockIdx.x & 7) * (nwg >> 3) + ((int)blockIdx.x >> 3);
    int bxA = wgid % MAB;
    int by  = wgid / MAB;
    const long a0 = (long)bxA * 256;
    const long b0 = (long)by * 256;

    // staging: per tile, 4 units of 512 chunks (16B): A rows 0-127 / 128-255,
    // B rows 0-127 / 128-255. chunk: row r=tid>>2, slot kc=tid&3;
    // swizzled source slot kc ^ ((r>>1)&3)  [same for r+128].
    const int r0  = tid >> 2;
    const int kc  = tid & 3;
    const int kcs = kc ^ ((r0 >> 1) & 3);
    const ushort_t* gA1 = A + (a0 + r0) * (long)KLEN + kcs * 8;
    const ushort_t* gA2 = gA1 + (long)128 * KLEN;
    const ushort_t* gB1 = B + (b0 + r0) * (long)KLEN + kcs * 8;
    const ushort_t* gB2 = gB1 + (long)128 * KLEN;

#define ST_A0(t) gload_lds16(gA1 + (long)(t) * 32, &L[(t) & 3][0][tid * 8])
#define ST_A1(t) gload_lds16(gA2 + (long)(t) * 32, &L[(t) & 3][0][(tid + 512) * 8])
#define ST_B0(t) gload_lds16(gB1 + (long)(t) * 32, &L[(t) & 3][1][tid * 8])
#define ST_B1(t) gload_lds16(gB2 + (long)(t) * 32, &L[(t) & 3][1][(tid + 512) * 8])

    f32x4 acc[8][4];
    #pragma unroll
    for (int m = 0; m < 8; ++m)
        #pragma unroll
        for (int n = 0; n < 4; ++n)
            acc[m][n] = (f32x4){0.f, 0.f, 0.f, 0.f};

    // ds_read fragment offsets (ushort units), swizzled slot lk^((lr>>1)&3)
    const int lks8 = (lk ^ ((lr >> 1) & 3)) * 8;
    const int roA = (wm * 128 + lr) * 32 + lks8;   // + m*512 per 16-row frag
    const int roB = (wn * 64 + lr) * 32 + lks8;    // + n*512

    // prologue: tiles 0,1,2 fully staged (12 loads/thread); tile0 guaranteed.
    ST_A0(0); ST_B0(0); ST_A1(0); ST_B1(0);
    ST_A0(1); ST_B0(1); ST_A1(1); ST_B1(1);
    ST_A0(2); ST_B0(2); ST_A1(2); ST_B1(2);
    asm volatile("s_waitcnt vmcnt(8)" ::: "memory");
    __builtin_amdgcn_sched_barrier(0);
    __builtin_amdgcn_s_barrier();

    #pragma unroll 1
    for (int t = 0; t < NT; ++t) {
        const ushort_t* bA = &L[t & 3][0][0];
        const ushort_t* bB = &L[t & 3][1][0];

        // ---------------- phase a ----------------
        s16x8 av[4], bv[4];
        #pragma unroll
        for (int m = 0; m < 4; ++m) av[m] = *(const s16x8*)&bA[roA + m * 512];
        #pragma unroll
        for (int n = 0; n < 4; ++n) bv[n] = *(const s16x8*)&bB[roB + n * 512];
        if (t + 3 < NT) { ST_A0(t + 3); ST_B0(t + 3); }
        __builtin_amdgcn_s_barrier();
        asm volatile("s_waitcnt lgkmcnt(0)" ::: "memory");
        __builtin_amdgcn_sched_barrier(0);
        __builtin_amdgcn_s_setprio(1);
        #pragma unroll
        for (int m = 0; m < 4; ++m)
            #pragma unroll
            for (int n = 0; n < 4; ++n)
                acc[m][n] = __builtin_amdgcn_mfma_f32_16x16x32_bf16(av[m], bv[n], acc[m][n], 0, 0, 0);
        __builtin_amdgcn_s_setprio(0);
        __builtin_amdgcn_s_barrier();

        // ---------------- phase b ----------------
        s16x8 av2[4];
        #pragma unroll
        for (int m = 0; m < 4; ++m) av2[m] = *(const s16x8*)&bA[roA + (m + 4) * 512];
        if (t + 3 < NT) { ST_A1(t + 3); ST_B1(t + 3); }
        asm volatile("s_waitcnt vmcnt(8)" ::: "memory");
        __builtin_amdgcn_sched_barrier(0);
        __builtin_amdgcn_s_barrier();
        asm volatile("s_waitcnt lgkmcnt(0)" ::: "memory");
        __builtin_amdgcn_sched_barrier(0);
        __builtin_amdgcn_s_setprio(1);
        #pragma unroll
        for (int m = 0; m < 4; ++m)
            #pragma unroll
            for (int n = 0; n < 4; ++n)
                acc[m + 4][n] = __builtin_amdgcn_mfma_f32_16x16x32_bf16(av2[m], bv[n], acc[m + 4][n], 0, 0, 0);
        __builtin_amdgcn_s_setprio(0);
        __builtin_amdgcn_s_barrier();
    }
#undef ST_A0
#undef ST_A1
#undef ST_B0
#undef ST_B1

    if constexpr (EPI == 0) {
        // U[i,h] = bf16(sech2(C + b1[h]) * w2[h]); reg axis = h (contiguous)
        #pragma unroll
        for (int m = 0; m < 8; ++m) {
            long h0 = a0 + wm * 128 + m * 16 + lk * 4;
            f32x4 b1v = *(const f32x4*)(b1 + h0);
            f32x4 w2v = *(const f32x4*)(W2 + h0);
            #pragma unroll
            for (int n = 0; n < 4; ++n) {
                long i = b0 + wn * 64 + n * 16 + lr;
                u16x4 ub;
                #pragma unroll
                for (int j = 0; j < 4; ++j) {
                    float uu = acc[m][n][j] + b1v[j];
                    // sech^2(u) = 4e/(1+e)^2, e = exp(-2|u|)
                    float e = __expf(-2.0f * fabsf(uu));
                    float rc = 1.0f / (1.0f + e);
                    ub[j] = f2b(4.0f * e * rc * rc * w2v[j]);
                }
                *(u16x4*)(U + i * H_SZ + h0) = ub;
            }
        }
    } else {
        // p -= coef*mask*G ; q += 0.1*p/mass*mask ; qb = bf16(q). reg axis = d.
        #pragma unroll
        for (int n = 0; n < 4; ++n) {
            long i = b0 + wn * 64 + n * 16 + lr;
            int id = ids[i];
            float cm = (id != 0) ? coef : 0.f;
            float hm = (id != 0) ? H_STEP : 0.f;
            float im = inv_mass[(int)(i & (S_SZ - 1))];
            #pragma unroll
            for (int m = 0; m < 8; ++m) {
                long d0 = a0 + wm * 128 + m * 16 + lk * 4;
                size_t off = (size_t)i * D_SZ + d0;
                f32x4 pv = *(const f32x4*)(p + off);
                #pragma unroll
                for (int j = 0; j < 4; ++j)
                    pv[j] -= cm * acc[m][n][j];
                *(f32x4*)(p + off) = pv;
                if (do_q) {
                    f32x4 qv = *(const f32x4*)(q + off);
                    u16x4 qbv;
                    #pragma unroll
                    for (int j = 0; j < 4; ++j) {
                        qv[j] += hm * pv[j] * im;
                        qbv[j] = f2b(qv[j]);
                    }
                    *(f32x4*)(q + off) = qv;
                    *(u16x4*)(qb + off) = qbv;
                }
            }
        }
    }
}

// ---------------- host launch ----------------
extern "C" void kernel_launch(void* const* d_in, const int* in_sizes, int n_in,
                              void* d_out, int out_size, void* d_ws, size_t ws_size,
                              hipStream_t stream) {
    const float* table = (const float*)d_in[0];
    const float* logm  = (const float*)d_in[1];
    const float* W1    = (const float*)d_in[2];
    const float* b1    = (const float*)d_in[3];
    const float* W2    = (const float*)d_in[4];
    // d_in[5] = b2, unused by the force (only shifts the potential value)
    const int*   ids   = (const int*)d_in[6];

    float* q = (float*)d_out;                       // [BS, D]
    float* p = q + (size_t)BS_SZ * D_SZ;            // [BS, D]

    char* ws = (char*)d_ws;
    size_t o = 0;
    ushort_t* qb  = (ushort_t*)(ws + o); o += (size_t)BS_SZ * D_SZ * 2;   // 32 MB
    ushort_t* U   = (ushort_t*)(ws + o); o += (size_t)BS_SZ * H_SZ * 2;   // 128 MB
    ushort_t* W1b = (ushort_t*)(ws + o); o += (size_t)H_SZ * D_SZ * 2;    // 2 MB
    ushort_t* W1T = (ushort_t*)(ws + o); o += (size_t)D_SZ * H_SZ * 2;    // 2 MB
    float* inv_mass = (float*)(ws + o);  o += S_SZ * 4;
    float* mass     = (float*)(ws + o);  o += S_SZ * 4;

    prep_w1<<<(H_SZ * D_SZ) / 256, 256, 0, stream>>>(W1, W1b, W1T);
    prep_mass<<<(S_SZ + 255) / 256, 256, 0, stream>>>(logm, inv_mass, mass);
    embed_kernel<<<BS_SZ, 128, 0, stream>>>(table, ids, mass, q, p, qb);

    // 6 distinct force evals: j=0 -> +0.05*f(q0); j=1..4 -> +0.1*f(qj); j=5 -> +0.05*f(q5)
    for (int j = 0; j < 6; ++j) {
        // force1: A = W1b [2048 rows], B = qb [32768 rows], K=512 -> grid 8*128
        gemmT<512, 8, 0><<<1024, 512, 0, stream>>>(
            W1b, qb, b1, W2, U, nullptr, nullptr, nullptr, nullptr, nullptr, 0.f, 0);
        float coef = (j == 0 || j == 5) ? 0.05f : 0.1f;
        // force2: A = W1T [512 rows], B = U [32768 rows], K=2048 -> grid 2*128
        gemmT<2048, 2, 1><<<256, 512, 0, stream>>>(
            W1T, U, nullptr, nullptr, nullptr, ids, inv_mass, q, p, qb, coef, (j < 5) ? 1 : 0);
    }
}